// Round 1
// baseline (404.934 us; speedup 1.0000x reference)
//
#include <hip/hip_runtime.h>

#define H_IN   128
#define W_IN   128
#define HW_IN  16384
#define C_IN   256
#define CC     64
#define HO     64
#define WO     64
#define HWO    4096
#define NB     4
#define NCH    44   // 25 mask + 16 kenc + 3 pad

// workspace layout (float element offsets)
#define OFF_WT    0            // 256*64       = 16384   (w_comp transposed [c][cc])
#define OFF_WALL  16384        // 576*44       = 25344   (enc+kenc transposed [ci*9+k][ch])
#define OFF_CX    41728        // 4*64*16384   = 4194304 (compressed features)
#define OFF_PART  4236032      // 4*4*44*4096  = 2883584 (encoder partial sums, ci-quarters)
#define OFF_MASK  7119616      // 4*25*4096    = 409600  (softmaxed masks)
// total 7529216 floats = 30.1 MB

__global__ __launch_bounds__(256) void prep_kernel(
    const float* __restrict__ wc, const float* __restrict__ we,
    const float* __restrict__ wk, float* __restrict__ ws) {
  int i = blockIdx.x * 256 + threadIdx.x;   // 41728 threads
  if (i < 16384) {
    int c = i >> 6, cc = i & 63;
    ws[OFF_WT + i] = wc[cc * C_IN + c];     // Wt[c][cc]
  } else {
    int e = i - 16384;                      // < 25344
    int row = e / NCH;                      // ci*9 + (kh*3+kw)
    int j = e - row * NCH;
    float v = 0.f;
    if (j < 25)      v = we[j * 576 + row];         // w_enc[o][ci][kh][kw]
    else if (j < 41) v = wk[(j - 25) * 576 + row];  // w_kenc
    ws[OFF_WALL + row * NCH + j] = v;
  }
}

// 1x1 conv: cx[b][cc][p] = sum_c x[b][c][p] * W[cc][c] + b_comp[cc]
__global__ __launch_bounds__(256) void compress_kernel(
    const float* __restrict__ x, const float* __restrict__ bcomp,
    const float* __restrict__ wsr, float* __restrict__ cx) {
  const float* Wt = wsr + OFF_WT;
  int g = blockIdx.x * 256 + threadIdx.x;
  int b = g >> 14, p = g & (HW_IN - 1);
  const float* xb = x + (size_t)b * C_IN * HW_IN + p;
  float acc[CC];
#pragma unroll
  for (int cc = 0; cc < CC; ++cc) acc[cc] = 0.f;
  for (int c0 = 0; c0 < C_IN; c0 += 8) {
    float xv[8];
#pragma unroll
    for (int u = 0; u < 8; ++u) xv[u] = xb[(size_t)(c0 + u) * HW_IN];
#pragma unroll
    for (int u = 0; u < 8; ++u) {
      const float* w = Wt + (c0 + u) * CC;   // block-uniform -> s_load
#pragma unroll
      for (int cc = 0; cc < CC; ++cc) acc[cc] = fmaf(w[cc], xv[u], acc[cc]);
    }
  }
  float* cxb = cx + (size_t)b * CC * HW_IN + p;
#pragma unroll
  for (int cc = 0; cc < CC; ++cc) cxb[(size_t)cc * HW_IN] = acc[cc] + bcomp[cc];
}

// 3x3 stride-2 conv, partial over ci-quarter q: part[q][b][ch][pix]
__global__ __launch_bounds__(256) void encoder_kernel(
    const float* __restrict__ wsr, float* __restrict__ part) {
  const float* cxall = wsr + OFF_CX;
  const float* wall  = wsr + OFF_WALL;
  int q = blockIdx.x >> 6;                       // ci-quarter 0..3
  int t = (blockIdx.x & 63) * 256 + threadIdx.x; // pixel id over B*HWO
  int b = t >> 12, pix = t & 4095;
  int ho = pix >> 6, wo = pix & 63;
  const float* cxb = cxall + (size_t)b * CC * HW_IN;
  float acc[NCH];
#pragma unroll
  for (int j = 0; j < NCH; ++j) acc[j] = 0.f;
  for (int ci = q * 16; ci < q * 16 + 16; ++ci) {
    const float* base = cxb + (size_t)ci * HW_IN;
#pragma unroll
    for (int kh = 0; kh < 3; ++kh) {
      int hi = 2 * ho - 1 + kh;
      if ((unsigned)hi < 128u) {               // wave-uniform branch
#pragma unroll
        for (int kw = 0; kw < 3; ++kw) {
          int wi = 2 * wo - 1 + kw;
          int wic = wi < 0 ? 0 : (wi > 127 ? 127 : wi);
          float v = base[hi * W_IN + wic];
          v = ((unsigned)wi < 128u) ? v : 0.f;
          const float* w = wall + (ci * 9 + kh * 3 + kw) * NCH;  // uniform -> s_load
#pragma unroll
          for (int j = 0; j < NCH; ++j) acc[j] = fmaf(w[j], v, acc[j]);
        }
      }
    }
  }
  float* pb = part + (size_t)(q * NB + b) * NCH * HWO + pix;
#pragma unroll
  for (int j = 0; j < NCH; ++j) pb[(size_t)j * HWO] = acc[j];
}

// reduce partials + bias, temperature = clip(prod ke,-10,10), softmax over 25
__global__ __launch_bounds__(256) void softmax_kernel(
    const float* __restrict__ wsr, const float* __restrict__ benc,
    const float* __restrict__ bkenc, float* __restrict__ mask) {
  const float* part = wsr + OFF_PART;
  int t = blockIdx.x * 256 + threadIdx.x;   // 16384 threads
  int b = t >> 12, pix = t & 4095;
  float lg[41];
#pragma unroll
  for (int ch = 0; ch < 41; ++ch) {
    float s = (ch < 25) ? benc[ch] : bkenc[ch - 25];
#pragma unroll
    for (int qq = 0; qq < 4; ++qq)
      s += part[((size_t)(qq * NB + b) * NCH + ch) * HWO + pix];
    lg[ch] = s;
  }
  float prod = lg[25];
#pragma unroll
  for (int ch = 26; ch < 41; ++ch) prod *= lg[ch];
  float iv = fminf(fmaxf(prod, -10.f), 10.f);
  float m = -1e30f;
#pragma unroll
  for (int ch = 0; ch < 25; ++ch) { lg[ch] *= iv; m = fmaxf(m, lg[ch]); }
  float sum = 0.f;
#pragma unroll
  for (int ch = 0; ch < 25; ++ch) { lg[ch] = __expf(lg[ch] - m); sum += lg[ch]; }
  float inv = 1.0f / sum;
#pragma unroll
  for (int ch = 0; ch < 25; ++ch)
    mask[(size_t)(b * 25 + ch) * HWO + pix] = lg[ch] * inv;
}

// out[b][c][ho][wo] = sum_k mask[b][k][ho][wo] * x[b][c][2ho-2+kh][2wo-2+kw]
__global__ __launch_bounds__(256) void reassemble_kernel(
    const float* __restrict__ x, const float* __restrict__ wsr,
    float* __restrict__ out) {
  const float* mask = wsr + OFF_MASK;
  int gb = blockIdx.x;                 // 256 blocks: [b][hog][cph]
  int cph = gb & 3, hog = (gb >> 2) & 15, b = gb >> 6;
  int wo = threadIdx.x & 63, hs = threadIdx.x >> 6;
  int ho = hog * 4 + hs;
  int opix = ho * WO + wo;
  float mk[25];
#pragma unroll
  for (int k = 0; k < 25; ++k)
    mk[k] = mask[(size_t)(b * 25 + k) * HWO + opix];
  for (int c = cph * 64; c < cph * 64 + 64; ++c) {
    const float* xb = x + (size_t)(b * C_IN + c) * HW_IN;
    float s = 0.f;
#pragma unroll
    for (int kh = 0; kh < 5; ++kh) {
      int hi = 2 * ho - 2 + kh;
      if ((unsigned)hi < 128u) {       // wave-uniform branch
#pragma unroll
        for (int kw = 0; kw < 5; ++kw) {
          int wi = 2 * wo - 2 + kw;
          int wic = wi < 0 ? 0 : (wi > 127 ? 127 : wi);
          float v = xb[hi * W_IN + wic];
          v = ((unsigned)wi < 128u) ? v : 0.f;
          s = fmaf(mk[kh * 5 + kw], v, s);
        }
      }
    }
    out[(size_t)(b * C_IN + c) * HWO + opix] = s;
  }
}

extern "C" void kernel_launch(void* const* d_in, const int* in_sizes, int n_in,
                              void* d_out, int out_size, void* d_ws, size_t ws_size,
                              hipStream_t stream) {
  const float* x      = (const float*)d_in[0];
  const float* w_comp = (const float*)d_in[1];
  const float* b_comp = (const float*)d_in[2];
  const float* w_enc  = (const float*)d_in[3];
  const float* b_enc  = (const float*)d_in[4];
  const float* w_kenc = (const float*)d_in[5];
  const float* b_kenc = (const float*)d_in[6];
  float* ws  = (float*)d_ws;
  float* out = (float*)d_out;

  prep_kernel<<<163, 256, 0, stream>>>(w_comp, w_enc, w_kenc, ws);
  compress_kernel<<<256, 256, 0, stream>>>(x, b_comp, ws, ws + OFF_CX);
  encoder_kernel<<<256, 256, 0, stream>>>(ws, ws + OFF_PART);
  softmax_kernel<<<64, 256, 0, stream>>>(ws, b_enc, b_kenc, ws + OFF_MASK);
  reassemble_kernel<<<256, 256, 0, stream>>>(x, ws, out);
}

// Round 2
// 320.569 us; speedup vs baseline: 1.2632x; 1.2632x over previous
//
#include <hip/hip_runtime.h>

#define H_IN   128
#define W_IN   128
#define HW_IN  16384
#define C_IN   256
#define CC     64
#define HO     64
#define WO     64
#define HWO    4096
#define NB     4
#define NCH    44   // 25 mask + 16 kenc + 3 pad

// workspace layout (float element offsets)
#define OFF_WT    0            // 256*64       = 16384   (w_comp transposed [c][cc])
#define OFF_WALL  16384        // 576*44       = 25344   (enc+kenc transposed [ci*9+k][ch])
#define OFF_CX    41728        // 4*64*16384   = 4194304 (compressed features)
#define OFF_PART  4236032      // 4*4*44*4096  = 2883584 (encoder partial sums, ci-quarters)
#define OFF_MASK  7119616      // 4*25*4096    = 409600  (softmaxed masks)
// total 7529216 floats = 30.1 MB

__global__ __launch_bounds__(256) void prep_kernel(
    const float* __restrict__ wc, const float* __restrict__ we,
    const float* __restrict__ wk, float* __restrict__ ws) {
  int i = blockIdx.x * 256 + threadIdx.x;   // 41728 threads
  if (i < 16384) {
    int c = i >> 6, cc = i & 63;
    ws[OFF_WT + i] = wc[cc * C_IN + c];     // Wt[c][cc]
  } else {
    int e = i - 16384;                      // < 25344
    int row = e / NCH;                      // ci*9 + (kh*3+kw)
    int j = e - row * NCH;
    float v = 0.f;
    if (j < 25)      v = we[j * 576 + row];         // w_enc[o][ci][kh][kw]
    else if (j < 41) v = wk[(j - 25) * 576 + row];  // w_kenc
    ws[OFF_WALL + row * NCH + j] = v;
  }
}

// 1x1 conv: cx[b][cc][p] = sum_c x[b][c][p] * W[cc][c] + b_comp[cc]
// software-pipelined: prefetch next 8 channel values during FMA block
__global__ __launch_bounds__(256) void compress_kernel(
    const float* __restrict__ x, const float* __restrict__ bcomp,
    const float* __restrict__ wsr, float* __restrict__ cx) {
  const float* Wt = wsr + OFF_WT;
  int g = blockIdx.x * 256 + threadIdx.x;
  int b = g >> 14, p = g & (HW_IN - 1);
  const float* xb = x + (size_t)b * C_IN * HW_IN + p;
  float acc[CC];
#pragma unroll
  for (int cc = 0; cc < CC; ++cc) acc[cc] = 0.f;
  float xv[8];
#pragma unroll
  for (int u = 0; u < 8; ++u) xv[u] = xb[(size_t)u * HW_IN];
  for (int c0 = 0; c0 < C_IN - 8; c0 += 8) {
    float xn[8];
#pragma unroll
    for (int u = 0; u < 8; ++u) xn[u] = xb[(size_t)(c0 + 8 + u) * HW_IN];
#pragma unroll
    for (int u = 0; u < 8; ++u) {
      const float* w = Wt + (c0 + u) * CC;   // block-uniform -> s_load
#pragma unroll
      for (int cc = 0; cc < CC; ++cc) acc[cc] = fmaf(w[cc], xv[u], acc[cc]);
    }
#pragma unroll
    for (int u = 0; u < 8; ++u) xv[u] = xn[u];
  }
#pragma unroll
  for (int u = 0; u < 8; ++u) {            // epilogue c0 = 248
    const float* w = Wt + (C_IN - 8 + u) * CC;
#pragma unroll
    for (int cc = 0; cc < CC; ++cc) acc[cc] = fmaf(w[cc], xv[u], acc[cc]);
  }
  float* cxb = cx + (size_t)b * CC * HW_IN + p;
#pragma unroll
  for (int cc = 0; cc < CC; ++cc) cxb[(size_t)cc * HW_IN] = acc[cc] + bcomp[cc];
}

// 3x3 stride-2 conv, partial over ci-quarter q: part[q][b][ch][pix]
__global__ __launch_bounds__(256) void encoder_kernel(
    const float* __restrict__ wsr, float* __restrict__ part) {
  const float* cxall = wsr + OFF_CX;
  const float* wall  = wsr + OFF_WALL;
  int q = blockIdx.x >> 6;                       // ci-quarter 0..3
  int t = (blockIdx.x & 63) * 256 + threadIdx.x; // pixel id over B*HWO
  int b = t >> 12, pix = t & 4095;
  int ho = pix >> 6, wo = pix & 63;
  const float* cxb = cxall + (size_t)b * CC * HW_IN;
  float acc[NCH];
#pragma unroll
  for (int j = 0; j < NCH; ++j) acc[j] = 0.f;
  for (int ci = q * 16; ci < q * 16 + 16; ++ci) {
    const float* base = cxb + (size_t)ci * HW_IN;
#pragma unroll
    for (int kh = 0; kh < 3; ++kh) {
      int hi = 2 * ho - 1 + kh;
      if ((unsigned)hi < 128u) {               // wave-uniform branch
#pragma unroll
        for (int kw = 0; kw < 3; ++kw) {
          int wi = 2 * wo - 1 + kw;
          int wic = wi < 0 ? 0 : (wi > 127 ? 127 : wi);
          float v = base[hi * W_IN + wic];
          v = ((unsigned)wi < 128u) ? v : 0.f;
          const float* w = wall + (ci * 9 + kh * 3 + kw) * NCH;  // uniform -> s_load
#pragma unroll
          for (int j = 0; j < NCH; ++j) acc[j] = fmaf(w[j], v, acc[j]);
        }
      }
    }
  }
  float* pb = part + (size_t)(q * NB + b) * NCH * HWO + pix;
#pragma unroll
  for (int j = 0; j < NCH; ++j) pb[(size_t)j * HWO] = acc[j];
}

// reduce partials + bias, temperature = clip(prod ke,-10,10), softmax over 25
// 256 blocks x 64 threads: spread across all CUs
__global__ __launch_bounds__(64) void softmax_kernel(
    const float* __restrict__ wsr, const float* __restrict__ benc,
    const float* __restrict__ bkenc, float* __restrict__ mask) {
  const float* part = wsr + OFF_PART;
  int t = blockIdx.x * 64 + threadIdx.x;   // 16384 threads
  int b = t >> 12, pix = t & 4095;
  float lg[41];
#pragma unroll
  for (int ch = 0; ch < 41; ++ch) {
    float s = (ch < 25) ? benc[ch] : bkenc[ch - 25];
#pragma unroll
    for (int qq = 0; qq < 4; ++qq)
      s += part[((size_t)(qq * NB + b) * NCH + ch) * HWO + pix];
    lg[ch] = s;
  }
  float prod = lg[25];
#pragma unroll
  for (int ch = 26; ch < 41; ++ch) prod *= lg[ch];
  float iv = fminf(fmaxf(prod, -10.f), 10.f);
  float m = -1e30f;
#pragma unroll
  for (int ch = 0; ch < 25; ++ch) { lg[ch] *= iv; m = fmaxf(m, lg[ch]); }
  float sum = 0.f;
#pragma unroll
  for (int ch = 0; ch < 25; ++ch) { lg[ch] = __expf(lg[ch] - m); sum += lg[ch]; }
  float inv = 1.0f / sum;
#pragma unroll
  for (int ch = 0; ch < 25; ++ch)
    mask[(size_t)(b * 25 + ch) * HWO + pix] = lg[ch] * inv;
}

// out[b][c][ho][wo] = sum_k mask[b][k][ho][wo] * x[b][c][2ho-2+kh][2wo-2+kw]
// 4096 blocks: [b(4)][hog(16)][cg(64)], 4 channels per block, mask in regs
__global__ __launch_bounds__(256) void reassemble_kernel(
    const float* __restrict__ x, const float* __restrict__ wsr,
    float* __restrict__ out) {
  const float* mask = wsr + OFF_MASK;
  int gb = blockIdx.x;
  int cg = gb & 63, hog = (gb >> 6) & 15, b = gb >> 10;
  int wo = threadIdx.x & 63, hs = threadIdx.x >> 6;
  int ho = hog * 4 + hs;
  int opix = ho * WO + wo;
  float mk[25];
#pragma unroll
  for (int k = 0; k < 25; ++k)
    mk[k] = mask[(size_t)(b * 25 + k) * HWO + opix];
#pragma unroll
  for (int j = 0; j < 4; ++j) {
    int c = cg * 4 + j;
    const float* xb = x + (size_t)(b * C_IN + c) * HW_IN;
    float s = 0.f;
#pragma unroll
    for (int kh = 0; kh < 5; ++kh) {
      int hi = 2 * ho - 2 + kh;
      if ((unsigned)hi < 128u) {       // wave-uniform branch (hs fixed per wave)
#pragma unroll
        for (int kw = 0; kw < 5; ++kw) {
          int wi = 2 * wo - 2 + kw;
          int wic = wi < 0 ? 0 : (wi > 127 ? 127 : wi);
          float v = xb[hi * W_IN + wic];
          v = ((unsigned)wi < 128u) ? v : 0.f;
          s = fmaf(mk[kh * 5 + kw], v, s);
        }
      }
    }
    out[(size_t)(b * C_IN + c) * HWO + opix] = s;
  }
}

extern "C" void kernel_launch(void* const* d_in, const int* in_sizes, int n_in,
                              void* d_out, int out_size, void* d_ws, size_t ws_size,
                              hipStream_t stream) {
  const float* x      = (const float*)d_in[0];
  const float* w_comp = (const float*)d_in[1];
  const float* b_comp = (const float*)d_in[2];
  const float* w_enc  = (const float*)d_in[3];
  const float* b_enc  = (const float*)d_in[4];
  const float* w_kenc = (const float*)d_in[5];
  const float* b_kenc = (const float*)d_in[6];
  float* ws  = (float*)d_ws;
  float* out = (float*)d_out;

  prep_kernel<<<163, 256, 0, stream>>>(w_comp, w_enc, w_kenc, ws);
  compress_kernel<<<256, 256, 0, stream>>>(x, b_comp, ws, ws + OFF_CX);
  encoder_kernel<<<256, 256, 0, stream>>>(ws, ws + OFF_PART);
  softmax_kernel<<<256, 64, 0, stream>>>(ws, b_enc, b_kenc, ws + OFF_MASK);
  reassemble_kernel<<<4096, 256, 0, stream>>>(x, ws, out);
}

// Round 3
// 217.882 us; speedup vs baseline: 1.8585x; 1.4713x over previous
//
#include <hip/hip_runtime.h>

#define H_IN   128
#define W_IN   128
#define HW_IN  16384
#define C_IN   256
#define CC     64
#define HO     64
#define WO     64
#define HWO    4096
#define NB     4
#define NPX    16384   // B*HWO output pixels
#define NCHP   48      // padded encoder out channels (25 mask + 16 kenc + 7 pad)

// workspace layout (float element offsets)
#define OFF_WC    0            // 8*256*8  = 16384   compress W [ccg][c][8]
#define OFF_WE    16384        // 8*576*6  = 27648   encoder W [chg][ci*9+t][6]
#define OFF_CX    44032        // 4*64*16384 = 4194304
#define OFF_PART  4238336      // 2*48*16384 = 1572864  partials [kh][ch][px]
#define OFF_MASK  5811200      // 25*16384   = 409600   mask [k][px]
// total 6220800 floats = 24.9 MB

__global__ __launch_bounds__(256) void prep_kernel(
    const float* __restrict__ wc, const float* __restrict__ we,
    const float* __restrict__ wk, float* __restrict__ ws) {
  int i = blockIdx.x * 256 + threadIdx.x;   // 44032 threads
  if (i < 16384) {
    int ccg = i >> 11, c = (i >> 3) & 255, j = i & 7;
    ws[OFF_WC + i] = wc[(ccg * 8 + j) * C_IN + c];
  } else if (i < 44032) {
    int e = i - 16384;
    int chg = e / 3456, r = e - chg * 3456;
    int row = r / 6, j = r - row * 6;
    int ch = chg * 6 + j;
    float v = 0.f;
    if (ch < 25)      v = we[ch * 576 + row];
    else if (ch < 41) v = wk[(ch - 25) * 576 + row];
    ws[OFF_WE + e] = v;
  }
}

// 1x1 conv as GEMM: 16 waves = (ccg 8 x kh 2); thread = 4 px x 8 cc
__global__ __launch_bounds__(1024) void compress_kernel(
    const float* __restrict__ x, const float* __restrict__ bcomp,
    const float* __restrict__ wsr, float* __restrict__ cx) {
  __shared__ float red[8][64][33];   // 67.6 KB, stride 33 -> conflict-free
  int tid = threadIdx.x;
  int wv = tid >> 6, lane = tid & 63;
  int ccg = __builtin_amdgcn_readfirstlane(wv & 7);
  int kh  = __builtin_amdgcn_readfirstlane(wv >> 3);
  int gq = blockIdx.x * 64 + lane;        // quad id (4 px each)
  int b = gq >> 12;
  int p = (gq & 4095) << 2;
  const float* xb = x + (size_t)b * C_IN * HW_IN + p;
  const float* wp = wsr + OFF_WC + ccg * (256 * 8);
  float4 acc[8];
#pragma unroll
  for (int j = 0; j < 8; ++j) acc[j] = make_float4(0.f, 0.f, 0.f, 0.f);
  int cbase = kh * 128;
  float4 xv[4], xn[4];
#pragma unroll
  for (int u = 0; u < 4; ++u)
    xv[u] = *(const float4*)(xb + (size_t)(cbase + u) * HW_IN);
  for (int c0 = 0; c0 < 128; c0 += 4) {
    if (c0 + 4 < 128) {
#pragma unroll
      for (int u = 0; u < 4; ++u)
        xn[u] = *(const float4*)(xb + (size_t)(cbase + c0 + 4 + u) * HW_IN);
    }
#pragma unroll
    for (int u = 0; u < 4; ++u) {
      const float* wrow = wp + (cbase + c0 + u) * 8;  // uniform -> s_load x16
      float4 xu = xv[u];
#pragma unroll
      for (int j = 0; j < 8; ++j) {
        float wj = wrow[j];
        acc[j].x = fmaf(wj, xu.x, acc[j].x);
        acc[j].y = fmaf(wj, xu.y, acc[j].y);
        acc[j].z = fmaf(wj, xu.z, acc[j].z);
        acc[j].w = fmaf(wj, xu.w, acc[j].w);
      }
    }
#pragma unroll
    for (int u = 0; u < 4; ++u) xv[u] = xn[u];
  }
  if (kh == 1) {
    float* d = &red[ccg][lane][0];
#pragma unroll
    for (int j = 0; j < 8; ++j) {
      d[j * 4 + 0] = acc[j].x; d[j * 4 + 1] = acc[j].y;
      d[j * 4 + 2] = acc[j].z; d[j * 4 + 3] = acc[j].w;
    }
  }
  __syncthreads();
  if (kh == 0) {
    const float* d = &red[ccg][lane][0];
#pragma unroll
    for (int j = 0; j < 8; ++j) {
      int cc = ccg * 8 + j;
      float bj = bcomp[cc];
      float4 o;
      o.x = acc[j].x + d[j * 4 + 0] + bj;
      o.y = acc[j].y + d[j * 4 + 1] + bj;
      o.z = acc[j].z + d[j * 4 + 2] + bj;
      o.w = acc[j].w + d[j * 4 + 3] + bj;
      *(float4*)(cx + ((size_t)b * CC + cc) * HW_IN + p) = o;
    }
  }
}

// 3x3 stride-2 conv: 16 waves = (chg 8 x kh 2); wave = one output row
__global__ __launch_bounds__(1024) void encoder_kernel(
    const float* __restrict__ wsr, float* __restrict__ part) {
  const float* cxall = wsr + OFF_CX;
  int tid = threadIdx.x;
  int wv = tid >> 6, lane = tid & 63;
  int chg = __builtin_amdgcn_readfirstlane(wv & 7);
  int kh  = __builtin_amdgcn_readfirstlane(wv >> 3);
  int px = blockIdx.x * 64 + lane;        // global output pixel
  int b = px >> 12, pix = px & 4095;
  int ho = pix >> 6, wo = pix & 63;       // ho uniform per block
  const float* cxb = cxall + (size_t)b * CC * HW_IN;
  const float* wbase = wsr + OFF_WE + chg * (576 * 6);
  float acc[6];
#pragma unroll
  for (int j = 0; j < 6; ++j) acc[j] = 0.f;
  for (int ci = kh * 32; ci < kh * 32 + 32; ++ci) {
    const float* base = cxb + (size_t)ci * HW_IN;
#pragma unroll
    for (int k3 = 0; k3 < 3; ++k3) {
      int hi = 2 * ho - 1 + k3;
      if ((unsigned)hi < 128u) {          // block-uniform branch
#pragma unroll
        for (int kw = 0; kw < 3; ++kw) {
          int wi = 2 * wo - 1 + kw;
          int wic = wi < 0 ? 0 : (wi > 127 ? 127 : wi);
          float v = base[hi * W_IN + wic];
          v = ((unsigned)wi < 128u) ? v : 0.f;
          const float* w = wbase + (ci * 9 + k3 * 3 + kw) * 6;  // uniform
#pragma unroll
          for (int j = 0; j < 6; ++j) acc[j] = fmaf(w[j], v, acc[j]);
        }
      }
    }
  }
  float* pb = part + (size_t)kh * NCHP * NPX + px;
#pragma unroll
  for (int j = 0; j < 6; ++j) pb[(size_t)(chg * 6 + j) * NPX] = acc[j];
}

// reduce partials + bias, temperature, softmax over 25 -> mask[k][px]
__global__ __launch_bounds__(64) void softmax_kernel(
    const float* __restrict__ wsr, const float* __restrict__ benc,
    const float* __restrict__ bkenc, float* __restrict__ mask) {
  const float* part = wsr + OFF_PART;
  int px = blockIdx.x * 64 + threadIdx.x;   // 16384 threads
  float lg[41];
#pragma unroll
  for (int ch = 0; ch < 41; ++ch) {
    float s = (ch < 25) ? benc[ch] : bkenc[ch - 25];
    s += part[(size_t)ch * NPX + px];
    s += part[(size_t)(NCHP + ch) * NPX + px];
    lg[ch] = s;
  }
  float prod = lg[25];
#pragma unroll
  for (int ch = 26; ch < 41; ++ch) prod *= lg[ch];
  float iv = fminf(fmaxf(prod, -10.f), 10.f);
  float m = -1e30f;
#pragma unroll
  for (int ch = 0; ch < 25; ++ch) { lg[ch] *= iv; m = fmaxf(m, lg[ch]); }
  float sum = 0.f;
#pragma unroll
  for (int ch = 0; ch < 25; ++ch) { lg[ch] = __expf(lg[ch] - m); sum += lg[ch]; }
  float inv = 1.0f / sum;
#pragma unroll
  for (int ch = 0; ch < 25; ++ch)
    mask[(size_t)ch * NPX + px] = lg[ch] * inv;
}

// out[b][c][ho][wo] = sum_k mask[k][px] * x[b][c][2ho-2+kh][2wo-2+kw]
__global__ __launch_bounds__(256) void reassemble_kernel(
    const float* __restrict__ x, const float* __restrict__ wsr,
    float* __restrict__ out) {
  const float* mask = wsr + OFF_MASK;
  int gb = blockIdx.x;
  int cg = gb & 63, hog = (gb >> 6) & 15, b = gb >> 10;
  int wo = threadIdx.x & 63, hs = threadIdx.x >> 6;
  int ho = hog * 4 + hs;
  int opix = ho * WO + wo;
  int gpx = b * HWO + opix;
  float mk[25];
#pragma unroll
  for (int k = 0; k < 25; ++k)
    mk[k] = mask[(size_t)k * NPX + gpx];
#pragma unroll
  for (int j = 0; j < 4; ++j) {
    int c = cg * 4 + j;
    const float* xb = x + (size_t)(b * C_IN + c) * HW_IN;
    float s = 0.f;
#pragma unroll
    for (int kh = 0; kh < 5; ++kh) {
      int hi = 2 * ho - 2 + kh;
      if ((unsigned)hi < 128u) {       // wave-uniform branch
#pragma unroll
        for (int kw = 0; kw < 5; ++kw) {
          int wi = 2 * wo - 2 + kw;
          int wic = wi < 0 ? 0 : (wi > 127 ? 127 : wi);
          float v = xb[hi * W_IN + wic];
          v = ((unsigned)wi < 128u) ? v : 0.f;
          s = fmaf(mk[kh * 5 + kw], v, s);
        }
      }
    }
    out[(size_t)(b * C_IN + c) * HWO + opix] = s;
  }
}

extern "C" void kernel_launch(void* const* d_in, const int* in_sizes, int n_in,
                              void* d_out, int out_size, void* d_ws, size_t ws_size,
                              hipStream_t stream) {
  const float* x      = (const float*)d_in[0];
  const float* w_comp = (const float*)d_in[1];
  const float* b_comp = (const float*)d_in[2];
  const float* w_enc  = (const float*)d_in[3];
  const float* b_enc  = (const float*)d_in[4];
  const float* w_kenc = (const float*)d_in[5];
  const float* b_kenc = (const float*)d_in[6];
  float* ws  = (float*)d_ws;
  float* out = (float*)d_out;

  prep_kernel<<<172, 256, 0, stream>>>(w_comp, w_enc, w_kenc, ws);
  compress_kernel<<<256, 1024, 0, stream>>>(x, b_comp, ws, ws + OFF_CX);
  encoder_kernel<<<256, 1024, 0, stream>>>(ws, ws + OFF_PART);
  softmax_kernel<<<256, 64, 0, stream>>>(ws, b_enc, b_kenc, ws + OFF_MASK);
  reassemble_kernel<<<4096, 256, 0, stream>>>(x, ws, out);
}

// Round 4
// 195.589 us; speedup vs baseline: 2.0703x; 1.1140x over previous
//
#include <hip/hip_runtime.h>

#define H_IN   128
#define W_IN   128
#define HW_IN  16384
#define C_IN   256
#define CC     64
#define HO     64
#define WO     64
#define HWO    4096
#define NB     4
#define NPX    16384   // B*HWO output pixels
#define NCHP   48      // padded encoder out channels (25 mask + 16 kenc + 7 pad)

// workspace layout (float element offsets)
#define OFF_WC    0            // 8*256*8  = 16384   compress W [ccg][c][8]
#define OFF_WE    16384        // 8*576*6  = 27648   encoder W [chg][ci*9+t][6]
#define OFF_CX    44032        // 4*64*16384 = 4194304
#define OFF_PART  4238336      // 2*48*16384 = 1572864  partials [kh][ch][px]
#define OFF_MASK  5811200      // 25*16384   = 409600   mask [k][px]
// total 6220800 floats = 24.9 MB

__global__ __launch_bounds__(256) void prep_kernel(
    const float* __restrict__ wc, const float* __restrict__ we,
    const float* __restrict__ wk, float* __restrict__ ws) {
  int i = blockIdx.x * 256 + threadIdx.x;   // 44032 threads
  if (i < 16384) {
    int ccg = i >> 11, c = (i >> 3) & 255, j = i & 7;
    ws[OFF_WC + i] = wc[(ccg * 8 + j) * C_IN + c];
  } else if (i < 44032) {
    int e = i - 16384;
    int chg = e / 3456, r = e - chg * 3456;
    int row = r / 6, j = r - row * 6;
    int ch = chg * 6 + j;
    float v = 0.f;
    if (ch < 25)      v = we[ch * 576 + row];
    else if (ch < 41) v = wk[(ch - 25) * 576 + row];
    ws[OFF_WE + e] = v;
  }
}

// 1x1 conv as GEMM: 16 waves = (ccg 8 x kh 2); thread = 4 px x 8 cc
__global__ __launch_bounds__(1024) void compress_kernel(
    const float* __restrict__ x, const float* __restrict__ bcomp,
    const float* __restrict__ wsr, float* __restrict__ cx) {
  __shared__ float red[8][64][33];   // 67.6 KB, stride 33 -> conflict-free
  int tid = threadIdx.x;
  int wv = tid >> 6, lane = tid & 63;
  int ccg = __builtin_amdgcn_readfirstlane(wv & 7);
  int kh  = __builtin_amdgcn_readfirstlane(wv >> 3);
  int gq = blockIdx.x * 64 + lane;        // quad id (4 px each)
  int b = gq >> 12;
  int p = (gq & 4095) << 2;
  const float* xb = x + (size_t)b * C_IN * HW_IN + p;
  const float* wp = wsr + OFF_WC + ccg * (256 * 8);
  float4 acc[8];
#pragma unroll
  for (int j = 0; j < 8; ++j) acc[j] = make_float4(0.f, 0.f, 0.f, 0.f);
  int cbase = kh * 128;
  float4 xv[4], xn[4];
#pragma unroll
  for (int u = 0; u < 4; ++u)
    xv[u] = *(const float4*)(xb + (size_t)(cbase + u) * HW_IN);
  for (int c0 = 0; c0 < 128; c0 += 4) {
    if (c0 + 4 < 128) {
#pragma unroll
      for (int u = 0; u < 4; ++u)
        xn[u] = *(const float4*)(xb + (size_t)(cbase + c0 + 4 + u) * HW_IN);
    }
#pragma unroll
    for (int u = 0; u < 4; ++u) {
      const float* wrow = wp + (cbase + c0 + u) * 8;  // uniform -> s_load x16
      float4 xu = xv[u];
#pragma unroll
      for (int j = 0; j < 8; ++j) {
        float wj = wrow[j];
        acc[j].x = fmaf(wj, xu.x, acc[j].x);
        acc[j].y = fmaf(wj, xu.y, acc[j].y);
        acc[j].z = fmaf(wj, xu.z, acc[j].z);
        acc[j].w = fmaf(wj, xu.w, acc[j].w);
      }
    }
#pragma unroll
    for (int u = 0; u < 4; ++u) xv[u] = xn[u];
  }
  if (kh == 1) {
    float* d = &red[ccg][lane][0];
#pragma unroll
    for (int j = 0; j < 8; ++j) {
      d[j * 4 + 0] = acc[j].x; d[j * 4 + 1] = acc[j].y;
      d[j * 4 + 2] = acc[j].z; d[j * 4 + 3] = acc[j].w;
    }
  }
  __syncthreads();
  if (kh == 0) {
    const float* d = &red[ccg][lane][0];
#pragma unroll
    for (int j = 0; j < 8; ++j) {
      int cc = ccg * 8 + j;
      float bj = bcomp[cc];
      float4 o;
      o.x = acc[j].x + d[j * 4 + 0] + bj;
      o.y = acc[j].y + d[j * 4 + 1] + bj;
      o.z = acc[j].z + d[j * 4 + 2] + bj;
      o.w = acc[j].w + d[j * 4 + 3] + bj;
      *(float4*)(cx + ((size_t)b * CC + cc) * HW_IN + p) = o;
    }
  }
}

// 3x3 stride-2 conv: 16 waves = (chg 8 x kh 2); wave = one output row
__global__ __launch_bounds__(1024) void encoder_kernel(
    const float* __restrict__ wsr, float* __restrict__ part) {
  const float* cxall = wsr + OFF_CX;
  int tid = threadIdx.x;
  int wv = tid >> 6, lane = tid & 63;
  int chg = __builtin_amdgcn_readfirstlane(wv & 7);
  int kh  = __builtin_amdgcn_readfirstlane(wv >> 3);
  int px = blockIdx.x * 64 + lane;        // global output pixel
  int b = px >> 12, pix = px & 4095;
  int ho = pix >> 6, wo = pix & 63;       // ho uniform per block
  const float* cxb = cxall + (size_t)b * CC * HW_IN;
  const float* wbase = wsr + OFF_WE + chg * (576 * 6);
  float acc[6];
#pragma unroll
  for (int j = 0; j < 6; ++j) acc[j] = 0.f;
  for (int ci = kh * 32; ci < kh * 32 + 32; ++ci) {
    const float* base = cxb + (size_t)ci * HW_IN;
#pragma unroll
    for (int k3 = 0; k3 < 3; ++k3) {
      int hi = 2 * ho - 1 + k3;
      if ((unsigned)hi < 128u) {          // block-uniform branch
#pragma unroll
        for (int kw = 0; kw < 3; ++kw) {
          int wi = 2 * wo - 1 + kw;
          int wic = wi < 0 ? 0 : (wi > 127 ? 127 : wi);
          float v = base[hi * W_IN + wic];
          v = ((unsigned)wi < 128u) ? v : 0.f;
          const float* w = wbase + (ci * 9 + k3 * 3 + kw) * 6;  // uniform
#pragma unroll
          for (int j = 0; j < 6; ++j) acc[j] = fmaf(w[j], v, acc[j]);
        }
      }
    }
  }
  float* pb = part + (size_t)kh * NCHP * NPX + px;
#pragma unroll
  for (int j = 0; j < 6; ++j) pb[(size_t)(chg * 6 + j) * NPX] = acc[j];
}

// reduce partials + bias, temperature, softmax over 25 -> mask[k][px]
__global__ __launch_bounds__(64) void softmax_kernel(
    const float* __restrict__ wsr, const float* __restrict__ benc,
    const float* __restrict__ bkenc, float* __restrict__ mask) {
  const float* part = wsr + OFF_PART;
  int px = blockIdx.x * 64 + threadIdx.x;   // 16384 threads
  float lg[41];
#pragma unroll
  for (int ch = 0; ch < 41; ++ch) {
    float s = (ch < 25) ? benc[ch] : bkenc[ch - 25];
    s += part[(size_t)ch * NPX + px];
    s += part[(size_t)(NCHP + ch) * NPX + px];
    lg[ch] = s;
  }
  float prod = lg[25];
#pragma unroll
  for (int ch = 26; ch < 41; ++ch) prod *= lg[ch];
  float iv = fminf(fmaxf(prod, -10.f), 10.f);
  float m = -1e30f;
#pragma unroll
  for (int ch = 0; ch < 25; ++ch) { lg[ch] *= iv; m = fmaxf(m, lg[ch]); }
  float sum = 0.f;
#pragma unroll
  for (int ch = 0; ch < 25; ++ch) { lg[ch] = __expf(lg[ch] - m); sum += lg[ch]; }
  float inv = 1.0f / sum;
#pragma unroll
  for (int ch = 0; ch < 25; ++ch)
    mask[(size_t)ch * NPX + px] = lg[ch] * inv;
}

// LDS-staged reassembly: block = [b(4)][hog(16)][cg(64 x 4ch)], 4096 blocks.
// Stage 4ch x 11 rows x 132 cols (zero halo) into LDS via coalesced float4,
// then 25 ds_read_b32 (immediate offsets, 2-way bank alias = free) + 25 FMA.
__global__ __launch_bounds__(256) void reassemble_kernel(
    const float* __restrict__ x, const float* __restrict__ wsr,
    float* __restrict__ out) {
  __shared__ float lds[4][11][136];    // 23.9 KB -> 6 blocks/CU
  const float* mask = wsr + OFF_MASK;
  int tid = threadIdx.x;
  int gb = blockIdx.x;
  int cg = gb & 63, hog = (gb >> 6) & 15, b = gb >> 10;
  int hi0 = hog * 8 - 2;

  // zero the halo columns (idx 0..3 and 132..135 of each row)
  for (int i = tid; i < 352; i += 256) {
    int ch = i / 88; int r = i - ch * 88; int row = r >> 3; int p = r & 7;
    int idx = (p < 4) ? p : (128 + p);
    lds[ch][row][idx] = 0.f;
  }
  // stage interior: 4ch x 11 rows x 32 float4 (col offset +4 -> 16B aligned)
  for (int i = tid; i < 1408; i += 256) {
    int ch = i / 352; int r = i - ch * 352;
    int row = r >> 5, c4 = r & 31;
    int hi = hi0 + row;
    float4 v = make_float4(0.f, 0.f, 0.f, 0.f);
    if ((unsigned)hi < 128u) {
      int c = cg * 4 + ch;
      v = *(const float4*)(x + ((size_t)(b * C_IN + c) * HW_IN) + hi * W_IN + c4 * 4);
    }
    *(float4*)(&lds[ch][row][4 + c4 * 4]) = v;
  }
  __syncthreads();

  int wo = tid & 63, hs = tid >> 6;
  int ho = hog * 4 + hs;
  int opix = ho * WO + wo;
  int gpx = b * HWO + opix;
  float mk[25];
#pragma unroll
  for (int k = 0; k < 25; ++k)
    mk[k] = mask[(size_t)k * NPX + gpx];
#pragma unroll
  for (int ch = 0; ch < 4; ++ch) {
    const float* lp = &lds[ch][2 * hs][2 + 2 * wo];   // base; taps via imm offsets
    float s = 0.f;
#pragma unroll
    for (int kh = 0; kh < 5; ++kh)
#pragma unroll
      for (int kw = 0; kw < 5; ++kw)
        s = fmaf(mk[kh * 5 + kw], lp[kh * 136 + kw], s);
    int c = cg * 4 + ch;
    out[(size_t)(b * C_IN + c) * HWO + opix] = s;
  }
}

extern "C" void kernel_launch(void* const* d_in, const int* in_sizes, int n_in,
                              void* d_out, int out_size, void* d_ws, size_t ws_size,
                              hipStream_t stream) {
  const float* x      = (const float*)d_in[0];
  const float* w_comp = (const float*)d_in[1];
  const float* b_comp = (const float*)d_in[2];
  const float* w_enc  = (const float*)d_in[3];
  const float* b_enc  = (const float*)d_in[4];
  const float* w_kenc = (const float*)d_in[5];
  const float* b_kenc = (const float*)d_in[6];
  float* ws  = (float*)d_ws;
  float* out = (float*)d_out;

  prep_kernel<<<172, 256, 0, stream>>>(w_comp, w_enc, w_kenc, ws);
  compress_kernel<<<256, 1024, 0, stream>>>(x, b_comp, ws, ws + OFF_CX);
  encoder_kernel<<<256, 1024, 0, stream>>>(ws, ws + OFF_PART);
  softmax_kernel<<<256, 64, 0, stream>>>(ws, b_enc, b_kenc, ws + OFF_MASK);
  reassemble_kernel<<<4096, 256, 0, stream>>>(x, ws, out);
}